// Round 25
// baseline (228.213 us; speedup 1.0000x reference)
//
#include <hip/hip_runtime.h>

// Problem sizes (match reference)
#define NS0 300000
#define ND0 50000
#define NE0 800000
#define NS1 50000
#define ND1 8192
#define NE1 131072
#define IN_F 256
#define HID_F 128
#define SLOTS 64    // bucket-CSR capacity; indeg ~ Poisson(16), P(>=64) ~ 1e-19
#define NT16 (NS0 / 16)   // 18750 16-row tiles
#define GEMM_GRID 1024    // 512-thread blocks
#define BUILD_GRID 256    // 512-thread blocks

typedef __attribute__((ext_vector_type(8))) _Float16 half8_t;
typedef __attribute__((ext_vector_type(4))) _Float16 half4_t;
typedef __attribute__((ext_vector_type(4))) float f32x4;

// Workspace layout (4-byte words), all 16B-aligned:
#define OFF_OUTDEG0I 0
#define OFF_OUTDEG1I 300000
#define OFF_CNT0     350000
#define OFF_CNT1     400000
#define ZERO_WORDS   408192
#define OFF_EDGE0    408192
#define OFF_EDGE1    6808192
#define OFF_H1       7856768
#define OFF_W1T      14256768
#define OFF_G        14273152

// ---------------- init: blocks [0,128) zero counters; [128,160) cvt W1->w1t
__global__ __launch_bounds__(256) void k_init(
    int4* __restrict__ p, const float* __restrict__ W1,
    _Float16* __restrict__ w1t) {
  if (blockIdx.x < 128) {
    int i = blockIdx.x * 256 + threadIdx.x;
    for (; i < ZERO_WORDS / 4; i += 128 * 256) p[i] = make_int4(0, 0, 0, 0);
  } else {
    int i = (blockIdx.x - 128) * 256 + threadIdx.x;
    for (; i < IN_F * HID_F; i += 32 * 256) {
      int k = i >> 7, n = i & 127;
      w1t[n * 256 + k] = (_Float16)W1[i];
    }
  }
}

// ---------------- fused: blocks [0, BUILD_GRID) edge build (first dispatch
// wave -> overlaps); blocks [BUILD_GRID, +GEMM_GRID) dense GEMM g = x@W1.
// r25: OCCUPANCY play. Every r12..r24 variant held 16 B-frags (64 VGPR) ->
// VGPR_Count 84 -> 4 waves/SIMD bracket (m69) -> ~16 waves/CU; all structural
// levers were null because none changed wave count. Now: 512-thread blocks,
// 8 waves, each wave owns 16 cols -> 8 B-frags (32 VGPR), total ~55, forced
// by __launch_bounds__(512,8) -> 8 waves/SIMD -> 32 waves/CU (2x). Staging,
// swizzle, fragment maps identical to the proven r12/r20 code (rows r*8+wv).
// Epilogue: block-level double-buffered outT, full-256B-line g stores after
// the existing per-tile barrier (r16 write-amplification fix, race-free via
// the 2-buffer rotation).
#define LDB(p, o) (*reinterpret_cast<const half8_t*>((p) + (o)))
__global__ __launch_bounds__(512, 8) void k_gemm_build(
    const float* __restrict__ x, const _Float16* __restrict__ w1t,
    _Float16* __restrict__ g,
    const int* __restrict__ src0, const int* __restrict__ dst0,
    const float* __restrict__ ew0, int* __restrict__ outdeg0,
    int* __restrict__ cnt0, int2* __restrict__ edge0,
    const int* __restrict__ src1, const int* __restrict__ dst1,
    const float* __restrict__ ew1, int* __restrict__ outdeg1,
    int* __restrict__ cnt1, int2* __restrict__ edge1) {
  __shared__ __align__(16) _Float16 ldsA[2][16 * 256];  // 2 x 8KB, frag order
  __shared__ __align__(16) _Float16 outT[2][16 * 132];  // 2 x 4.1KB epilogue

  if (blockIdx.x < BUILD_GRID) {
    int tid = blockIdx.x * 512 + threadIdx.x;
    int stride = BUILD_GRID * 512;
    for (int i = tid; i < NE0; i += stride) {
      int s = src0[i];
      int d = dst0[i];
      float w = ew0[i];
      atomicAdd(&outdeg0[s], 1);
      int slot = atomicAdd(&cnt0[d], 1);
      if (slot < SLOTS) edge0[d * SLOTS + slot] = make_int2(s, __float_as_int(w));
    }
    for (int i = tid; i < NE1; i += stride) {
      int s = src1[i];
      int d = dst1[i];
      float w = ew1[i];
      atomicAdd(&outdeg1[s], 1);
      int slot = atomicAdd(&cnt1[d], 1);
      if (slot < SLOTS) edge1[d * SLOTS + slot] = make_int2(s, __float_as_int(w));
    }
    return;
  }

  // ---------------- GEMM path (8 waves, 16 cols per wave) ----------------
  const int tid = threadIdx.x;       // 0..511
  const int wv = tid >> 6;           // 0..7
  const int lane = tid & 63;
  const int m = lane & 15;
  const int grp = lane >> 4;

  // B-frag: lane holds W1[k = kb*32 + grp*8 + j][n = 16wv + m] — 8 regs only
  const _Float16* wb = w1t + (size_t)(16 * wv + m) * 256 + grp * 8;
  const half8_t b0 = LDB(wb, 0),   b1 = LDB(wb, 32),  b2 = LDB(wb, 64),
                b3 = LDB(wb, 96),  b4 = LDB(wb, 128), b5 = LDB(wb, 160),
                b6 = LDB(wb, 192), b7 = LDB(wb, 224);

  // staging constants (swizzle S = idx ^ skb ^ sgrp; proven r12)
  const int skb = lane >> 3;
  const int sgrp = (lane >> 1) & 3;
  const int sjh = lane & 1;

  const int bid = blockIdx.x - BUILD_GRID;
  float4 pv[2];

// thread covers row (r*8 + wv), cols lane*4..+4 — 2 dense 2KB-spaced loads
#define LOAD_PV(PV, T)                                                         \
  {                                                                            \
    const float* tb = x + (size_t)(T) * 4096;                                  \
    _Pragma("unroll") for (int r = 0; r < 2; ++r)                              \
        PV[r] = *reinterpret_cast<const float4*>(tb + tid * 4 + r * 2048);     \
  }

#define WRITE_LDS(BUFI, PV)                                                    \
  {                                                                            \
    char* Bp = reinterpret_cast<char*>(&ldsA[BUFI][0]);                        \
    _Pragma("unroll") for (int r = 0; r < 2; ++r) {                            \
      const int mr = r * 8 + wv;                                               \
      half4_t hv;                                                              \
      hv[0] = (_Float16)PV[r].x; hv[1] = (_Float16)PV[r].y;                    \
      hv[2] = (_Float16)PV[r].z; hv[3] = (_Float16)PV[r].w;                    \
      const int idx = skb * 64 + sgrp * 16 + mr;                               \
      const int S = idx ^ skb ^ sgrp;                                          \
      *reinterpret_cast<half4_t*>(Bp + S * 16 + sjh * 8) = hv;                 \
    }                                                                          \
  }

#define STEP(A, KB, B)                                                         \
  {                                                                            \
    const int Sr = ((KB * 64 + lane) ^ KB ^ grp);                              \
    const half8_t af = *reinterpret_cast<const half8_t*>(A + Sr * 16);         \
    acc = __builtin_amdgcn_mfma_f32_16x16x32_f16(af, B, acc, 0, 0, 0);         \
  }

// compute tile from ldsA[BUFI] and deposit D into outT[BUFI] (16x16 patch)
#define COMPUTE(BUFI)                                                          \
  {                                                                            \
    const char* A = reinterpret_cast<const char*>(&ldsA[BUFI][0]);             \
    f32x4 acc = {0.f, 0.f, 0.f, 0.f};                                          \
    STEP(A, 0, b0) STEP(A, 1, b1) STEP(A, 2, b2) STEP(A, 3, b3)                \
    STEP(A, 4, b4) STEP(A, 5, b5) STEP(A, 6, b6) STEP(A, 7, b7)                \
    _Pragma("unroll") for (int r = 0; r < 4; ++r)                              \
        outT[BUFI][(4 * grp + r) * 132 + 16 * wv + m] = (_Float16)acc[r];      \
  }

// full-line store: thread emits 8B of row (tid>>5) -> 16 dense 256B rows
#define STORE_G(T, BUFI)                                                       \
  {                                                                            \
    const int srow = tid >> 5;                                                 \
    const int scol = (tid & 31) * 4;                                           \
    const half4_t ov = *reinterpret_cast<const half4_t*>(                      \
        &outT[BUFI][srow * 132 + scol]);                                       \
    *reinterpret_cast<half4_t*>(                                               \
        g + ((size_t)(T) * 16 + srow) * 128 + scol) = ov;                      \
  }

  // prologue: stage tile bid into buf 0
  LOAD_PV(pv, bid);
  WRITE_LDS(0, pv);
  __syncthreads();

  int cur = 0;
  for (int t = bid; t < NT16; t += GEMM_GRID) {
    const int nxt = t + GEMM_GRID;
    if (nxt < NT16) LOAD_PV(pv, nxt);   // issue next tile's loads
    COMPUTE(cur);                        // 8 MFMA/wave; D -> outT[cur]
    if (nxt < NT16) WRITE_LDS(cur ^ 1, pv);
    __syncthreads();                     // publishes ldsA[cur^1] AND outT[cur]
    STORE_G(t, cur);                     // full-line g store (cross-wave read)
    cur ^= 1;
  }
#undef LOAD_PV
#undef WRITE_LDS
#undef STEP
#undef COMPUTE
#undef STORE_G
}

// ---------------- layer-1 aggregation over g (fp16, 77 MB, L3-resident):
// h1[d] = relu(rsqrt(indeg)*sum ew*rsqrt(outdeg0[src])*g[src] + b1) * rsqrt(outdeg1[d])
__global__ __launch_bounds__(256) void k_gather1(
    const _Float16* __restrict__ g, const int* __restrict__ cnt,
    const int2* __restrict__ edge, const int* __restrict__ outdeg0,
    const int* __restrict__ outdeg1, const float* __restrict__ b1,
    float* __restrict__ h1) {
  const int w = (blockIdx.x * 256 + threadIdx.x) >> 6;  // dst row
  const int lane = threadIdx.x & 63;
  const int gp = lane >> 4;
  const int sl = lane & 15;
  if (w >= ND0) return;
  const int deg = min(cnt[w], SLOTS);
  const int2* ep = edge + (size_t)w * SLOTS;
  float acc[8] = {0.f, 0.f, 0.f, 0.f, 0.f, 0.f, 0.f, 0.f};
  for (int e = 0; e < deg; e += 4) {
    const int idx = e + gp;
    int2 p = make_int2(0, 0);
    float c = 0.f;
    if (idx < deg) {
      p = ep[idx];
      c = __int_as_float(p.y) * rsqrtf(fmaxf((float)outdeg0[p.x], 1.0f));
    }
    const half8_t v =
        *reinterpret_cast<const half8_t*>(g + (size_t)p.x * 128 + sl * 8);
#pragma unroll
    for (int j = 0; j < 8; ++j) acc[j] = fmaf(c, (float)v[j], acc[j]);
  }
#pragma unroll
  for (int j = 0; j < 8; ++j) {
    acc[j] += __shfl_xor(acc[j], 16, 64);
    acc[j] += __shfl_xor(acc[j], 32, 64);
  }
  if (gp == 0) {
    const float sc = rsqrtf(fmaxf((float)deg, 1.0f));
    const float s1 = rsqrtf(fmaxf((float)outdeg1[w], 1.0f));
    const float4 bv0 = *reinterpret_cast<const float4*>(b1 + sl * 8);
    const float4 bv1 = *reinterpret_cast<const float4*>(b1 + sl * 8 + 4);
    float4 o0, o1;
    o0.x = fmaxf(fmaf(acc[0], sc, bv0.x), 0.0f) * s1;
    o0.y = fmaxf(fmaf(acc[1], sc, bv0.y), 0.0f) * s1;
    o0.z = fmaxf(fmaf(acc[2], sc, bv0.z), 0.0f) * s1;
    o0.w = fmaxf(fmaf(acc[3], sc, bv0.w), 0.0f) * s1;
    o1.x = fmaxf(fmaf(acc[4], sc, bv1.x), 0.0f) * s1;
    o1.y = fmaxf(fmaf(acc[5], sc, bv1.y), 0.0f) * s1;
    o1.z = fmaxf(fmaf(acc[6], sc, bv1.z), 0.0f) * s1;
    o1.w = fmaxf(fmaf(acc[7], sc, bv1.w), 0.0f) * s1;
    float* hr = h1 + (size_t)w * 128 + sl * 8;
    *reinterpret_cast<float4*>(hr) = o0;
    *reinterpret_cast<float4*>(hr + 4) = o1;
  }
}

#define FMA2(acc, c, v)        \
  acc.x = fmaf(c, v.x, acc.x); \
  acc.y = fmaf(c, v.y, acc.y);

// --------------------------------------------- fused gather + GEMM, layer 2
__global__ __launch_bounds__(256) void k_layer2(
    const float* __restrict__ h1, const int* __restrict__ cnt,
    const int2* __restrict__ edge, const float* __restrict__ W2,
    const float* __restrict__ b2, float* __restrict__ out) {
  __shared__ float arow[8][HID_F];
  const int t = blockIdx.x;
  const int wv = threadIdx.x >> 6;
  const int lane = threadIdx.x & 63;

#pragma unroll
  for (int rr = 0; rr < 2; ++rr) {
    const int row = t * 8 + wv * 2 + rr;
    const int deg = min(cnt[row], SLOTS);
    const int2* ep = edge + (size_t)row * SLOTS;
    float2 acc = make_float2(0.f, 0.f);
    int e = 0;
    for (; e + 4 <= deg; e += 4) {
      int4 q0 = *reinterpret_cast<const int4*>(ep + e);
      int4 q1 = *reinterpret_cast<const int4*>(ep + e + 2);
      float2 v0 = *reinterpret_cast<const float2*>(h1 + (size_t)q0.x * HID_F + lane * 2);
      float2 v1 = *reinterpret_cast<const float2*>(h1 + (size_t)q0.z * HID_F + lane * 2);
      float2 v2 = *reinterpret_cast<const float2*>(h1 + (size_t)q1.x * HID_F + lane * 2);
      float2 v3 = *reinterpret_cast<const float2*>(h1 + (size_t)q1.z * HID_F + lane * 2);
      FMA2(acc, __int_as_float(q0.y), v0);
      FMA2(acc, __int_as_float(q0.w), v1);
      FMA2(acc, __int_as_float(q1.y), v2);
      FMA2(acc, __int_as_float(q1.w), v3);
    }
    for (; e < deg; ++e) {
      int2 p = ep[e];
      float2 v = *reinterpret_cast<const float2*>(h1 + (size_t)p.x * HID_F + lane * 2);
      FMA2(acc, __int_as_float(p.y), v);
    }
    const float sc = rsqrtf(fmaxf((float)deg, 1.0f));
    *reinterpret_cast<float2*>(&arow[wv * 2 + rr][lane * 2]) =
        make_float2(acc.x * sc, acc.y * sc);
  }
  __syncthreads();

  const int j = threadIdx.x & 127;
  const int rg = threadIdx.x >> 7;
  float a0 = 0.f, a1 = 0.f, a2 = 0.f, a3 = 0.f;
  const float* wj = W2 + j;
#pragma unroll 8
  for (int k = 0; k < HID_F; ++k) {
    const float wvv = wj[(size_t)k * 128];
    a0 = fmaf(arow[rg * 4 + 0][k], wvv, a0);
    a1 = fmaf(arow[rg * 4 + 1][k], wvv, a1);
    a2 = fmaf(arow[rg * 4 + 2][k], wvv, a2);
    a3 = fmaf(arow[rg * 4 + 3][k], wvv, a3);
  }
  const float bj = b2[j];
  const int row0 = t * 8 + rg * 4;
  out[(size_t)(row0 + 0) * 128 + j] = fmaxf(a0 + bj, 0.0f);
  out[(size_t)(row0 + 1) * 128 + j] = fmaxf(a1 + bj, 0.0f);
  out[(size_t)(row0 + 2) * 128 + j] = fmaxf(a2 + bj, 0.0f);
  out[(size_t)(row0 + 3) * 128 + j] = fmaxf(a3 + bj, 0.0f);
}

extern "C" void kernel_launch(void* const* d_in, const int* in_sizes, int n_in,
                              void* d_out, int out_size, void* d_ws, size_t ws_size,
                              hipStream_t stream) {
  const float* x    = (const float*)d_in[0];
  const int*   src0 = (const int*)d_in[1];
  const int*   dst0 = (const int*)d_in[2];
  const float* ew0  = (const float*)d_in[3];
  const int*   src1 = (const int*)d_in[4];
  const int*   dst1 = (const int*)d_in[5];
  const float* ew1  = (const float*)d_in[6];
  const float* W1   = (const float*)d_in[7];
  const float* b1   = (const float*)d_in[8];
  const float* W2   = (const float*)d_in[9];
  const float* b2   = (const float*)d_in[10];
  float* out = (float*)d_out;

  int*   wsi = (int*)d_ws;
  float* wsf = (float*)d_ws;
  int* outdeg0 = wsi + OFF_OUTDEG0I;
  int* outdeg1 = wsi + OFF_OUTDEG1I;
  int* cnt0    = wsi + OFF_CNT0;
  int* cnt1    = wsi + OFF_CNT1;
  int2* edge0  = (int2*)(wsi + OFF_EDGE0);
  int2* edge1  = (int2*)(wsi + OFF_EDGE1);
  float* h1    = wsf + OFF_H1;
  _Float16* w1t = (_Float16*)(wsi + OFF_W1T);
  _Float16* g   = (_Float16*)(wsi + OFF_G);

  k_init<<<160, 256, 0, stream>>>((int4*)d_ws, W1, w1t);
  k_gemm_build<<<BUILD_GRID + GEMM_GRID, 512, 0, stream>>>(
      x, w1t, g, src0, dst0, ew0, outdeg0, cnt0, edge0,
      src1, dst1, ew1, outdeg1, cnt1, edge1);
  k_gather1<<<(ND0 * 64) / 256, 256, 0, stream>>>(g, cnt0, edge0, outdeg0,
                                                  outdeg1, b1, h1);
  k_layer2<<<ND1 / 8, 256, 0, stream>>>(h1, cnt1, edge1, W2, b2, out);
}